// Round 1
// baseline (320.576 us; speedup 1.0000x reference)
//
#include <hip/hip_runtime.h>

// out[0,z,r,c,ch] = in[0, zi[z], ri[r], ci[c], 0]
// in : (1,128,128,128,32) f32 ; out : (1,64,64,64,32) f32
//
// 1M threads. Thread i writes float4 #i (covers z in [0,32)) and
// float4 #(i + 2^20) (same r,c,channel-group, z+32). Within a 256-thread
// block, z and r are uniform -> zi/ri gathers become scalar loads.

__global__ __launch_bounds__(256) void ds3d_kernel(
    const float* __restrict__ in,
    const int* __restrict__ zi,
    const int* __restrict__ ri,
    const int* __restrict__ ci,
    float4* __restrict__ out)
{
    const int bid = blockIdx.x;        // 0..4095
    const int tid = threadIdx.x;       // 0..255

    const int i    = (bid << 8) + tid; // linear float4 index, 0 .. 2^20-1
    const int cell = i >> 3;           // (z,r,c) cell, z in [0,32)
    const int c    = cell & 63;

    // Block-uniform index gathers -> compiler emits s_load (z,r constant per block:
    // a block spans 32 consecutive cells; 32 | 64 and 32 | 4096, so no carry).
    const int iz1 = zi[bid >> 7];          // z      = cell>>12
    const int iz2 = zi[(bid >> 7) + 32];   // z + 32 (second half of output)
    const int ir  = ri[(bid >> 1) & 63];   // r      = (cell>>6)&63
    const int ic  = ci[c];                 // per-lane

    // element index = ((iz*128 + ir)*128 + ic)*32
    const int coloff = (ir << 12) + (ic << 5);
    const float v1 = in[(iz1 << 19) + coloff];
    const float v2 = in[(iz2 << 19) + coloff];

    out[i]             = make_float4(v1, v1, v1, v1);
    out[i + (1 << 20)] = make_float4(v2, v2, v2, v2);
}

extern "C" void kernel_launch(void* const* d_in, const int* in_sizes, int n_in,
                              void* d_out, int out_size, void* d_ws, size_t ws_size,
                              hipStream_t stream)
{
    const float* in = (const float*)d_in[0];
    const int*   zi = (const int*)d_in[1];
    const int*   ri = (const int*)d_in[2];
    const int*   ci = (const int*)d_in[3];
    float4* out = (float4*)d_out;

    // total float4 stores = 64*64*64*32/4 = 2,097,152 ; 2 per thread
    const int block = 256;
    const int grid  = (64 * 64 * 64 * 8 / 2) / block;  // 4096
    ds3d_kernel<<<grid, block, 0, stream>>>(in, zi, ri, ci, out);
}